// Round 1
// baseline (140.980 us; speedup 1.0000x reference)
//
#include <hip/hip_runtime.h>
#include <hip/hip_bf16.h>
#include <math.h>

// ChamferLoss: pred [32,4096,3] f32, gt [32,4096,3] f32 -> scalar f32.
//
// min_m d2 = p2 + min_m (g2[m] - 2*dot)  -> 3 FMA + 1 min per pair (scalar).
//
// R5 post-mortem of R4: VALUBusy 68%, Occupancy 17.5%. Busy time (60us) is
// already ~the fp32-FMA issue floor (v_pk_fma_f32 is 4cy/wave-inst, capped by
// the 157TF fp32 pipe -> floor ~48us); the loss is the 32% IDLE time from
// only 2 blocks/CU (8 waves) -> lgkmcnt waits + end-of-kernel atomic burst
// are not hidden. R5:
//  - Split queries 2-way (QPT 16->8, grid 512->1024 = 4 blocks/CU,
//    16 waves/CU). Query-split (unlike more target-splits) keeps the
//    atomicMin merge count at 8 per query.
//  - __launch_bounds__(256,4).
//  - Read-guard before atomicMin: monotonic-decreasing min makes a stale
//    plain load safe-conservative; skips most contended atomics.
//  - finish: 64 blocks x 16 elems (was 256 x 4) -> 4x fewer serialized
//    same-address atomicAdds.

#define TPB   256
#define QPT   8             // queries per thread; 2048 per block
#define QP    (QPT / 2)     // packed query pairs
#define NPTS  4096
#define TSPL  8             // target split (8 x 512)
#define QSPL  2             // query split  (2 x 2048)
#define TCH   (NPTS / TSPL) // 512 targets per block (8 KB LDS)
#define QCH   (NPTS / QSPL) // 2048 queries per block
#define NQTOT (2 * 32 * NPTS)

typedef float vf2 __attribute__((ext_vector_type(2)));
typedef float vf4 __attribute__((ext_vector_type(4)));

// d = q * bcast(g.lo) + bcast(g.hi)   [one v_pk_fma_f32]
__device__ __forceinline__ vf2 pk_fma_blo_bhi(vf2 q, vf2 g) {
    vf2 d;
    asm("v_pk_fma_f32 %0, %1, %2, %3 op_sel:[0,0,1] op_sel_hi:[1,0,1]"
        : "=v"(d) : "v"(q), "v"(g), "v"(g));
    return d;
}
// d = q * bcast(g.hi) + c
__device__ __forceinline__ vf2 pk_fma_bhi(vf2 q, vf2 g, vf2 c) {
    vf2 d;
    asm("v_pk_fma_f32 %0, %1, %2, %3 op_sel:[0,1,0] op_sel_hi:[1,1,1]"
        : "=v"(d) : "v"(q), "v"(g), "v"(c));
    return d;
}
// d = q * bcast(g.lo) + c
__device__ __forceinline__ vf2 pk_fma_blo(vf2 q, vf2 g, vf2 c) {
    vf2 d;
    asm("v_pk_fma_f32 %0, %1, %2, %3 op_sel:[0,0,0] op_sel_hi:[1,0,1]"
        : "=v"(d) : "v"(q), "v"(g), "v"(c));
    return d;
}

__global__ __launch_bounds__(TPB, 4) void chamfer_main(
    const float* __restrict__ pred,
    const float* __restrict__ gt,
    unsigned int* __restrict__ wsmin)
{
    // grid.x = 1024: dir (2) x batch (32) x tsplit (8) x qsplit (2)
    const int bx  = blockIdx.x;
    const int dir = bx >> 9;
    const int rem = bx & 511;
    const int b   = rem >> 4;
    const int sub = rem & 15;
    const int kt  = sub >> 1;
    const int qs  = sub & 1;

    const float* __restrict__ qbase = (dir ? gt : pred) + (size_t)b * NPTS * 3
                                      + (size_t)qs * QCH * 3;
    const float* __restrict__ tbase = (dir ? pred : gt) + (size_t)b * NPTS * 3;

    __shared__ vf4 sT[TCH];     // (-2x, -2y, -2z, x^2+y^2+z^2)  8 KB

    const int tid = threadIdx.x;

    // Stage this block's 512-target slice: 2 points per thread
    for (int j = tid; j < TCH; j += TPB) {
        const float* tp = tbase + (size_t)(kt * TCH + j) * 3;
        float x = tp[0], y = tp[1], z = tp[2];
        vf4 t; t[0] = -2.0f * x; t[1] = -2.0f * y; t[2] = -2.0f * z;
        t[3] = fmaf(x, x, fmaf(y, y, z * z));
        sT[j] = t;
    }

    // Load 8 queries per thread, packed 2-per-register-pair
    vf2 qx2[QP], qy2[QP], qz2[QP];
    float mn[QPT];
#pragma unroll
    for (int p = 0; p < QP; ++p) {
#pragma unroll
        for (int h = 0; h < 2; ++h) {
            const int i = 2 * p + h;
            const float* q = qbase + (size_t)(i * TPB + tid) * 3;
            qx2[p][h] = q[0]; qy2[p][h] = q[1]; qz2[p][h] = q[2];
            mn[i] = 1e30f;
        }
    }

    __syncthreads();

    // 2 targets x 4 query-pairs per iter: 24 pk_fma + 8 min3 = 32 VALU
    // insts per 2 ds_read_b128 (broadcast-uniform addr -> conflict-free).
#pragma unroll 2
    for (int j = 0; j < TCH; j += 2) {
        const vf4 G0 = sT[j];
        const vf4 G1 = sT[j + 1];
        const vf2 g0xy = __builtin_shufflevector(G0, G0, 0, 1);
        const vf2 g0zw = __builtin_shufflevector(G0, G0, 2, 3);
        const vf2 g1xy = __builtin_shufflevector(G1, G1, 0, 1);
        const vf2 g1zw = __builtin_shufflevector(G1, G1, 2, 3);
#pragma unroll
        for (int p = 0; p < QP; ++p) {
            vf2 d0 = pk_fma_blo_bhi(qz2[p], g0zw);   // qz*g.z + g.w
            d0 = pk_fma_bhi(qy2[p], g0xy, d0);       // + qy*g.y
            d0 = pk_fma_blo(qx2[p], g0xy, d0);       // + qx*g.x
            vf2 d1 = pk_fma_blo_bhi(qz2[p], g1zw);
            d1 = pk_fma_bhi(qy2[p], g1xy, d1);
            d1 = pk_fma_blo(qx2[p], g1xy, d1);
            mn[2 * p]     = fminf(fminf(d0[0], d1[0]), mn[2 * p]);     // v_min3
            mn[2 * p + 1] = fminf(fminf(d0[1], d1[1]), mn[2 * p + 1]); // v_min3
        }
    }

    // d2 = p2 + min, clamp >=1e-12 (positive -> uint order == float order);
    // merge across the 8 sibling tsplit blocks with atomicMin, guarded by a
    // plain load (values only decrease -> stale read is safe-conservative).
    unsigned int* wq = wsmin + (size_t)(dir * 32 + b) * NPTS + (size_t)qs * QCH;
#pragma unroll
    for (int p = 0; p < QP; ++p) {
        vf2 p2 = qx2[p] * qx2[p] + qy2[p] * qy2[p] + qz2[p] * qz2[p];
#pragma unroll
        for (int h = 0; h < 2; ++h) {
            const int i = 2 * p + h;
            float d2 = fmaxf(mn[i] + p2[h], 1e-12f);
            unsigned int mine = __float_as_uint(d2);
            if (mine < wq[i * TPB + tid])
                atomicMin(&wq[i * TPB + tid], mine);
        }
    }
}

// sqrt + mean over all 262144 query mins, accumulate into out[0].
// 64 blocks x 16 elems/thread -> only 64 serialized atomicAdds on out[0].
#define FIN_EPT 16
__global__ __launch_bounds__(TPB) void chamfer_finish(
    const unsigned int* __restrict__ wsmin,
    float* __restrict__ out)
{
    __shared__ float swave[TPB / 64];
    const int tid  = threadIdx.x;
    const int base = blockIdx.x * (TPB * FIN_EPT) + tid;

    float s = 0.0f;
#pragma unroll
    for (int r = 0; r < FIN_EPT; ++r) {
        float d2 = __uint_as_float(wsmin[base + r * TPB]);
        s += sqrtf(d2);
    }

#pragma unroll
    for (int off = 32; off > 0; off >>= 1)
        s += __shfl_down(s, off, 64);
    const int wid = tid >> 6, lane = tid & 63;
    if (lane == 0) swave[wid] = s;
    __syncthreads();
    if (tid == 0) {
        float tot = swave[0] + swave[1] + swave[2] + swave[3];
        atomicAdd(out, tot * (1.0f / 131072.0f));
    }
}

extern "C" void kernel_launch(void* const* d_in, const int* in_sizes, int n_in,
                              void* d_out, int out_size, void* d_ws, size_t ws_size,
                              hipStream_t stream)
{
    const float* pred = (const float*)d_in[0];
    const float* gt   = (const float*)d_in[1];
    float* out        = (float*)d_out;
    unsigned int* wsmin = (unsigned int*)d_ws;

    // Identity for uint atomicMin: 0xFFFFFFFF. Zero the scalar output.
    hipMemsetAsync(d_ws, 0xFF, (size_t)NQTOT * sizeof(unsigned int), stream);
    hipMemsetAsync(d_out, 0, sizeof(float), stream);

    chamfer_main<<<dim3(1024), dim3(TPB), 0, stream>>>(pred, gt, wsmin);
    chamfer_finish<<<dim3(NQTOT / (TPB * FIN_EPT)), dim3(TPB), 0, stream>>>(wsmin, out);
}